// Round 6
// baseline (117.657 us; speedup 1.0000x reference)
//
#include <hip/hip_runtime.h>
#include <hip/hip_bf16.h>

typedef __attribute__((ext_vector_type(8))) short bf16x8;
typedef __attribute__((ext_vector_type(4))) float f32x4;
typedef __attribute__((ext_vector_type(4))) unsigned short u16x4;
typedef __attribute__((ext_vector_type(8))) unsigned short u16x8;

// ws layout (ushort units):
//   Qb [4][4096][8]  @ 0        bf16, pre-scaled by 0.125, [n][c] fragment layout
//   Kb [4][4096][8]  @ 131072   bf16, [m][c]
//   Vb [4][64][4096] @ 262144   bf16, [v][n]
//   avg floats [4][64] @ ushort offset 1310720 (zeroed via memsetAsync)
#define WS_QB 0
#define WS_KB 131072
#define WS_VB 262144
#define WS_AVG_U 1310720

__device__ __forceinline__ unsigned short bf_hi(float x) {
    __hip_bfloat16 h = __float2bfloat16(x);
    return *reinterpret_cast<unsigned short*>(&h);
}

// ---------------------------------------------------------------------------
// Kernel A: QKV projection (MFMA) + channel means. grid = 1280 x 256.
// bid: tile = bid>>8 (0..4), pair = bid&255: b = pair>>6, n64 = pair&63.
// ---------------------------------------------------------------------------
__global__ __launch_bounds__(256) void proj_kernel(
    const float* __restrict__ x,
    const float* __restrict__ Wq, const float* __restrict__ bq,
    const float* __restrict__ Wk, const float* __restrict__ bk,
    const float* __restrict__ Wv, const float* __restrict__ bv,
    unsigned short* __restrict__ Qb, unsigned short* __restrict__ Kb,
    unsigned short* __restrict__ Vb, float* __restrict__ avg)
{
    __shared__ __align__(16) unsigned short Wls[16 * 72];

    const int tid = threadIdx.x;
    const int w = tid >> 6;
    const int l = tid & 63;
    const int g = l >> 4;
    const int l15 = l & 15;

    const int tile = blockIdx.x >> 8;
    const int pair = blockIdx.x & 255;
    const int b = pair >> 6;
    const int n0 = (pair & 63) << 6;
    const int n = n0 + w * 16 + l15;
    const float* xb = x + b * 262144;

    float xr[2][8];
#pragma unroll
    for (int kcb = 0; kcb < 2; ++kcb)
#pragma unroll
        for (int j = 0; j < 8; ++j)
            xr[kcb][j] = xb[(kcb * 32 + g * 8 + j) * 4096 + n];

#pragma unroll
    for (int i = 0; i < 4; ++i) {
        const int idx = i * 256 + tid;
        const int row = idx >> 6, col = idx & 63;
        float wv;
        if (tile == 0) wv = (row < 8) ? Wq[row * 64 + col] : Wk[(row - 8) * 64 + col];
        else           wv = Wv[((tile - 1) * 16 + row) * 64 + col];
        Wls[row * 72 + col] = bf_hi(wv);
    }
    __syncthreads();

    bf16x8 bfr[2];
#pragma unroll
    for (int kcb = 0; kcb < 2; ++kcb)
#pragma unroll
        for (int j = 0; j < 8; ++j)
            bfr[kcb][j] = (short)bf_hi(xr[kcb][j]);

    const bf16x8 a0 = *(const bf16x8*)&Wls[l15 * 72 + g * 8];
    const bf16x8 a1 = *(const bf16x8*)&Wls[l15 * 72 + 32 + g * 8];
    f32x4 acc;
#pragma unroll
    for (int r = 0; r < 4; ++r) acc[r] = 0.0f;
    acc = __builtin_amdgcn_mfma_f32_16x16x32_bf16(a0, bfr[0], acc, 0, 0, 0);
    acc = __builtin_amdgcn_mfma_f32_16x16x32_bf16(a1, bfr[1], acc, 0, 0, 0);

    if (tile == 0) {
        u16x4 ov;
        if (g < 2) {
#pragma unroll
            for (int r = 0; r < 4; ++r) ov[r] = bf_hi((acc[r] + bq[g * 4 + r]) * 0.125f);
            *(u16x4*)&Qb[(b * 4096 + n) * 8 + g * 4] = ov;
        } else {
#pragma unroll
            for (int r = 0; r < 4; ++r) ov[r] = bf_hi(acc[r] + bk[(g - 2) * 4 + r]);
            *(u16x4*)&Kb[(b * 4096 + n) * 8 + (g - 2) * 4] = ov;
        }
        const int c = tid >> 2;
        const float* xrow = xb + c * 4096 + n0 + ((tid & 3) << 4);
        float s = 0.0f;
#pragma unroll
        for (int k = 0; k < 4; ++k) {
            const float4 v = *(const float4*)&xrow[k * 4];
            s += (v.x + v.y) + (v.z + v.w);
        }
        s += __shfl_xor(s, 1);
        s += __shfl_xor(s, 2);
        if ((tid & 3) == 0) atomicAdd(&avg[b * 64 + c], s * (1.0f / 4096.0f));
    } else {
#pragma unroll
        for (int r = 0; r < 4; ++r) {
            const int v = (tile - 1) * 16 + g * 4 + r;
            Vb[(b * 64 + v) * 4096 + n] = bf_hi(acc[r] + bv[v]);
        }
    }
}

// ---------------------------------------------------------------------------
// Kernel B: attention + gate. grid = 512 (XCD-chunk-swizzled), 256 thr/4 waves.
// Block = (b, 32-query tile). NO in-loop barriers: each wave owns m-chunks
// c = w + 4*ci (32 m each) end-to-end:
//   QK via MFMA (K frag direct from global) -> exp -> P into WAVE-PRIVATE LDS
//   (double-buffered; within-wave DS ordering, no barrier) -> PV via MFMA
//   (V frags direct from global, L2-resident). Next chunk's K/V issued before
//   compute -> ~full chunk of latency cover, never drained by a barrier.
// End: partial O per wave -> LDS, one barrier, combine + z + gate epilogue.
// ---------------------------------------------------------------------------
__global__ __launch_bounds__(256, 2) void attn_kernel(
    const unsigned short* __restrict__ Qb, const unsigned short* __restrict__ Kb,
    const unsigned short* __restrict__ Vb, const float* __restrict__ avg,
    const float* __restrict__ W1, const float* __restrict__ b1,
    const float* __restrict__ W2, const float* __restrict__ b2,
    float* __restrict__ out)
{
    __shared__ __align__(16) unsigned short Pls[4][2][32][40]; // [wave][buf][q][m+pad]
    __shared__ float osum[4][64][33];                          // [wave][v][q+pad]
    __shared__ float zls[32], gls[64], avgs[64];

    const int t = threadIdx.x;
    const int w = t >> 6;
    const int l = t & 63;
    const int g = l >> 4;
    const int l15 = l & 15;

    // bijective XCD chunk swizzle (512 % 8 == 0)
    const int wg = (blockIdx.x & 7) * 64 + (blockIdx.x >> 3);
    const int b = wg >> 7;
    const int q0 = (wg & 127) << 5;

    if (t < 32) zls[t] = 0.0f;
    if (t < 64) avgs[t] = avg[b * 64 + t];
    __syncthreads();   // init visible before any wave's post-loop atomics

    bf16x8 zf = {};
    bf16x8 qf[2];
#pragma unroll
    for (int qt = 0; qt < 2; ++qt) {
        bf16x8 v = *(const bf16x8*)&Qb[(b * 4096 + q0 + qt * 16 + l15) * 8];
        qf[qt] = (g == 0) ? v : zf;
    }

    const unsigned short* kb = Kb + b * 4096 * 8;
    const unsigned short* vbB = Vb + (b * 64) * 4096;

    // prefetch chunk ci=0 (c = w, m0 = 32*w)
    int m0 = w * 32;
    bf16x8 kpa = zf, kpb = zf;
    if (g == 0) {
        kpa = *(const bf16x8*)&kb[(m0 + l15) * 8];
        kpb = *(const bf16x8*)&kb[(m0 + 16 + l15) * 8];
    }
    bf16x8 vp[4];
#pragma unroll
    for (int vt = 0; vt < 4; ++vt)
        vp[vt] = *(const bf16x8*)&vbB[(vt * 16 + l15) * 4096 + m0 + g * 8];

    f32x4 acc[2][4];
#pragma unroll
    for (int qt = 0; qt < 2; ++qt)
#pragma unroll
        for (int vt = 0; vt < 4; ++vt)
#pragma unroll
            for (int r = 0; r < 4; ++r) acc[qt][vt][r] = 0.0f;
    float zreg[2] = {0.f, 0.f};

    for (int ci = 0; ci < 32; ++ci) {
        // current chunk's operands
        const bf16x8 ka = kpa, kc = kpb;
        bf16x8 vc[4];
#pragma unroll
        for (int vt = 0; vt < 4; ++vt) vc[vt] = vp[vt];

        // issue next chunk's loads (covered by this chunk's compute)
        const int m0n = (ci < 31) ? (w + 4 * (ci + 1)) * 32 : m0;
        if (g == 0) {
            kpa = *(const bf16x8*)&kb[(m0n + l15) * 8];
            kpb = *(const bf16x8*)&kb[(m0n + 16 + l15) * 8];
        }
#pragma unroll
        for (int vt = 0; vt < 4; ++vt)
            vp[vt] = *(const bf16x8*)&vbB[(vt * 16 + l15) * 4096 + m0n + g * 8];

        // QK -> exp -> P (wave-private LDS buffer, parity ci&1)
        unsigned short* Pw = &Pls[w][ci & 1][0][0];
        f32x4 dz;
#pragma unroll
        for (int r = 0; r < 4; ++r) dz[r] = 0.0f;
#pragma unroll
        for (int mt = 0; mt < 2; ++mt) {
            const bf16x8 kf = mt ? kc : ka;
#pragma unroll
            for (int qt = 0; qt < 2; ++qt) {
                f32x4 d = __builtin_amdgcn_mfma_f32_16x16x32_bf16(kf, qf[qt], dz, 0, 0, 0);
                float p[4];
#pragma unroll
                for (int r = 0; r < 4; ++r) p[r] = __expf(d[r]);
                zreg[qt] += (p[0] + p[1]) + (p[2] + p[3]);
                u16x4 pw;
#pragma unroll
                for (int r = 0; r < 4; ++r) pw[r] = bf_hi(p[r]);
                *(u16x4*)&Pw[(qt * 16 + l15) * 40 + mt * 16 + g * 4] = pw;
            }
        }
        // P B-frags (same wave: DS in-order + compiler lgkmcnt, no barrier)
        const bf16x8 bp0 = *(const bf16x8*)&Pw[l15 * 40 + g * 8];
        const bf16x8 bp1 = *(const bf16x8*)&Pw[(16 + l15) * 40 + g * 8];

        // PV
        __builtin_amdgcn_s_setprio(1);
#pragma unroll
        for (int vt = 0; vt < 4; ++vt) {
            acc[0][vt] = __builtin_amdgcn_mfma_f32_16x16x32_bf16(vc[vt], bp0, acc[0][vt], 0, 0, 0);
            acc[1][vt] = __builtin_amdgcn_mfma_f32_16x16x32_bf16(vc[vt], bp1, acc[1][vt], 0, 0, 0);
        }
        __builtin_amdgcn_s_setprio(0);
        m0 = m0n;
    }

    // z: combine lane groups (l, l^16, l^32, l^48), one atomic per wave per q
#pragma unroll
    for (int qt = 0; qt < 2; ++qt) {
        float z = zreg[qt];
        z += __shfl_xor(z, 16);
        z += __shfl_xor(z, 32);
        if (g == 0) atomicAdd(&zls[qt * 16 + l15], z);
    }

    // per-wave partial O -> LDS
#pragma unroll
    for (int qt = 0; qt < 2; ++qt)
#pragma unroll
        for (int vt = 0; vt < 4; ++vt)
#pragma unroll
            for (int r = 0; r < 4; ++r)
                osum[w][vt * 16 + g * 4 + r][qt * 16 + l15] = acc[qt][vt][r];

    // SE gate (wave 0, tiny)
    if (t < 64) {
        float hreg[4];
#pragma unroll
        for (int j = 0; j < 4; ++j) {
            float hh = b1[j];
            for (int c = 0; c < 64; ++c) hh += W1[j * 64 + c] * avgs[c];
            hreg[j] = fmaxf(hh, 0.0f);
        }
        float gg = b2[t];
#pragma unroll
        for (int j = 0; j < 4; ++j) gg += W2[t * 4 + j] * hreg[j];
        gls[t] = 1.0f / (1.0f + __expf(-gg));
    }
    __syncthreads();

    // combine 4 wave-partials + scale + gate + store
    {
        const int v = t >> 2;
        const int qb4 = (t & 3) * 8;
        const float gv = gls[v];
        float* orow = out + (b * 64 + v) * 4096 + q0 + qb4;
#pragma unroll
        for (int j = 0; j < 8; ++j) {
            const int q = qb4 + j;
            const float s = (osum[0][v][q] + osum[1][v][q])
                          + (osum[2][v][q] + osum[3][v][q]);
            orow[j] = s * (1.0f / zls[q]) * gv;
        }
    }
}

extern "C" void kernel_launch(void* const* d_in, const int* in_sizes, int n_in,
                              void* d_out, int out_size, void* d_ws, size_t ws_size,
                              hipStream_t stream) {
    const float* x  = (const float*)d_in[0];
    const float* Wq = (const float*)d_in[1];
    const float* bq = (const float*)d_in[2];
    const float* Wk = (const float*)d_in[3];
    const float* bk = (const float*)d_in[4];
    const float* Wv = (const float*)d_in[5];
    const float* bv = (const float*)d_in[6];
    const float* W1 = (const float*)d_in[7];
    const float* b1 = (const float*)d_in[8];
    const float* W2 = (const float*)d_in[9];
    const float* b2 = (const float*)d_in[10];

    unsigned short* wsu = (unsigned short*)d_ws;
    unsigned short* Qb = wsu + WS_QB;
    unsigned short* Kb = wsu + WS_KB;
    unsigned short* Vb = wsu + WS_VB;
    float* avg = (float*)(wsu + WS_AVG_U);
    float* out = (float*)d_out;

    hipMemsetAsync(avg, 0, 256 * sizeof(float), stream);
    proj_kernel<<<1280, 256, 0, stream>>>(x, Wq, bq, Wk, bk, Wv, bv, Qb, Kb, Vb, avg);
    attn_kernel<<<512, 256, 0, stream>>>(Qb, Kb, Vb, avg, W1, b1, W2, b2, out);
}

// Round 7
// 117.573 us; speedup vs baseline: 1.0007x; 1.0007x over previous
//
#include <hip/hip_runtime.h>
#include <hip/hip_bf16.h>

typedef __attribute__((ext_vector_type(8))) short bf16x8;
typedef __attribute__((ext_vector_type(4))) float f32x4;
typedef __attribute__((ext_vector_type(4))) unsigned short u16x4;
typedef __attribute__((ext_vector_type(8))) unsigned short u16x8;

// ws layout (ushort units):
//   Qb [4][4096][8]  @ 0        bf16, pre-scaled by 0.125, [n][c] fragment layout
//   Kb [4][4096][8]  @ 131072   bf16, [m][c]
//   Vb [4][64][4096] @ 262144   bf16, [v][n]
//   avg floats [4][64] @ ushort offset 1310720 (zeroed via memsetAsync)
#define WS_QB 0
#define WS_KB 131072
#define WS_VB 262144
#define WS_AVG_U 1310720

__device__ __forceinline__ unsigned short bf_hi(float x) {
    __hip_bfloat16 h = __float2bfloat16(x);
    return *reinterpret_cast<unsigned short*>(&h);
}
__device__ __forceinline__ unsigned int bfpk(float lo, float hi) {
    return (unsigned int)bf_hi(lo) | ((unsigned int)bf_hi(hi) << 16);
}

// ---------------------------------------------------------------------------
// Kernel A: QKV projection (MFMA) + channel means. grid = 1280 x 256.
// ---------------------------------------------------------------------------
__global__ __launch_bounds__(256) void proj_kernel(
    const float* __restrict__ x,
    const float* __restrict__ Wq, const float* __restrict__ bq,
    const float* __restrict__ Wk, const float* __restrict__ bk,
    const float* __restrict__ Wv, const float* __restrict__ bv,
    unsigned short* __restrict__ Qb, unsigned short* __restrict__ Kb,
    unsigned short* __restrict__ Vb, float* __restrict__ avg)
{
    __shared__ __align__(16) unsigned short Wls[16 * 72];

    const int tid = threadIdx.x;
    const int w = tid >> 6;
    const int l = tid & 63;
    const int g = l >> 4;
    const int l15 = l & 15;

    const int tile = blockIdx.x >> 8;
    const int pair = blockIdx.x & 255;
    const int b = pair >> 6;
    const int n0 = (pair & 63) << 6;
    const int n = n0 + w * 16 + l15;
    const float* xb = x + b * 262144;

    float xr[2][8];
#pragma unroll
    for (int kcb = 0; kcb < 2; ++kcb)
#pragma unroll
        for (int j = 0; j < 8; ++j)
            xr[kcb][j] = xb[(kcb * 32 + g * 8 + j) * 4096 + n];

#pragma unroll
    for (int i = 0; i < 4; ++i) {
        const int idx = i * 256 + tid;
        const int row = idx >> 6, col = idx & 63;
        float wv;
        if (tile == 0) wv = (row < 8) ? Wq[row * 64 + col] : Wk[(row - 8) * 64 + col];
        else           wv = Wv[((tile - 1) * 16 + row) * 64 + col];
        Wls[row * 72 + col] = bf_hi(wv);
    }
    __syncthreads();

    bf16x8 bfr[2];
#pragma unroll
    for (int kcb = 0; kcb < 2; ++kcb)
#pragma unroll
        for (int j = 0; j < 8; ++j)
            bfr[kcb][j] = (short)bf_hi(xr[kcb][j]);

    const bf16x8 a0 = *(const bf16x8*)&Wls[l15 * 72 + g * 8];
    const bf16x8 a1 = *(const bf16x8*)&Wls[l15 * 72 + 32 + g * 8];
    f32x4 acc;
#pragma unroll
    for (int r = 0; r < 4; ++r) acc[r] = 0.0f;
    acc = __builtin_amdgcn_mfma_f32_16x16x32_bf16(a0, bfr[0], acc, 0, 0, 0);
    acc = __builtin_amdgcn_mfma_f32_16x16x32_bf16(a1, bfr[1], acc, 0, 0, 0);

    if (tile == 0) {
        u16x4 ov;
        if (g < 2) {
#pragma unroll
            for (int r = 0; r < 4; ++r) ov[r] = bf_hi((acc[r] + bq[g * 4 + r]) * 0.125f);
            *(u16x4*)&Qb[(b * 4096 + n) * 8 + g * 4] = ov;
        } else {
#pragma unroll
            for (int r = 0; r < 4; ++r) ov[r] = bf_hi(acc[r] + bk[(g - 2) * 4 + r]);
            *(u16x4*)&Kb[(b * 4096 + n) * 8 + (g - 2) * 4] = ov;
        }
        const int c = tid >> 2;
        const float* xrow = xb + c * 4096 + n0 + ((tid & 3) << 4);
        float s = 0.0f;
#pragma unroll
        for (int k = 0; k < 4; ++k) {
            const float4 v = *(const float4*)&xrow[k * 4];
            s += (v.x + v.y) + (v.z + v.w);
        }
        s += __shfl_xor(s, 1);
        s += __shfl_xor(s, 2);
        if ((tid & 3) == 0) atomicAdd(&avg[b * 64 + c], s * (1.0f / 4096.0f));
    } else {
#pragma unroll
        for (int r = 0; r < 4; ++r) {
            const int v = (tile - 1) * 16 + g * 4 + r;
            Vb[(b * 64 + v) * 4096 + n] = bf_hi(acc[r] + bv[v]);
        }
    }
}

// ---------------------------------------------------------------------------
// Kernel B: attention + gate. grid = 512 (XCD-chunk-swizzled), 256 thr/4 waves,
// 4 blocks/CU. Block = (b, 32-query tile). Each wave owns m-chunks w+4*ci.
// NO in-loop LDS / barriers. P redistribution QK-D -> PV-B in registers:
//   pack P pairs to bf16 words; one shfl_xor(16) swap (odd lanes send mt=0
//   words, even send mt=1) leaves lane g holding m-slice tau(g)=bitrev(g);
//   tau is absorbed into the V A-frag load offset (k-permutation invariant).
// ---------------------------------------------------------------------------
__global__ __launch_bounds__(256, 4) void attn_kernel(
    const unsigned short* __restrict__ Qb, const unsigned short* __restrict__ Kb,
    const unsigned short* __restrict__ Vb, const float* __restrict__ avg,
    const float* __restrict__ W1, const float* __restrict__ b1,
    const float* __restrict__ W2, const float* __restrict__ b2,
    float* __restrict__ out)
{
    __shared__ float osum[4][64][33];   // [wave][v][q+pad]
    __shared__ float zls[32], gls[64], avgs[64];

    const int t = threadIdx.x;
    const int w = t >> 6;
    const int l = t & 63;
    const int g = l >> 4;
    const int l15 = l & 15;
    const int godd = g & 1;
    const int gs = (godd << 1) | (g >> 1);   // tau(g): bit-reversed 2-bit g

    // bijective XCD chunk swizzle (512 % 8 == 0)
    const int wg = (blockIdx.x & 7) * 64 + (blockIdx.x >> 3);
    const int b = wg >> 7;
    const int q0 = (wg & 127) << 5;

    if (t < 32) zls[t] = 0.0f;
    if (t < 64) avgs[t] = avg[b * 64 + t];
    __syncthreads();   // init visible before post-loop atomics/reads

    bf16x8 zf = {};
    bf16x8 qf[2];
#pragma unroll
    for (int qt = 0; qt < 2; ++qt) {
        bf16x8 v = *(const bf16x8*)&Qb[(b * 4096 + q0 + qt * 16 + l15) * 8];
        qf[qt] = (g == 0) ? v : zf;
    }

    const unsigned short* kb = Kb + b * 4096 * 8;
    const unsigned short* vbB = Vb + (b * 64) * 4096;

    // prefetch chunk ci=0 (m0 = 32*w); V frags at slice tau(g)
    int m0 = w * 32;
    bf16x8 kpa = zf, kpb = zf;
    if (g == 0) {
        kpa = *(const bf16x8*)&kb[(m0 + l15) * 8];
        kpb = *(const bf16x8*)&kb[(m0 + 16 + l15) * 8];
    }
    bf16x8 vp[4];
#pragma unroll
    for (int vt = 0; vt < 4; ++vt)
        vp[vt] = *(const bf16x8*)&vbB[(vt * 16 + l15) * 4096 + m0 + gs * 8];

    f32x4 acc[2][4];
#pragma unroll
    for (int qt = 0; qt < 2; ++qt)
#pragma unroll
        for (int vt = 0; vt < 4; ++vt)
#pragma unroll
            for (int r = 0; r < 4; ++r) acc[qt][vt][r] = 0.0f;
    float zreg[2] = {0.f, 0.f};

    for (int ci = 0; ci < 32; ++ci) {
        const bf16x8 ka = kpa, kc = kpb;
        bf16x8 vc[4];
#pragma unroll
        for (int vt = 0; vt < 4; ++vt) vc[vt] = vp[vt];

        // issue next chunk's loads (covered by this chunk's compute)
        const int m0n = (ci < 31) ? (w + 4 * (ci + 1)) * 32 : m0;
        if (g == 0) {
            kpa = *(const bf16x8*)&kb[(m0n + l15) * 8];
            kpb = *(const bf16x8*)&kb[(m0n + 16 + l15) * 8];
        }
#pragma unroll
        for (int vt = 0; vt < 4; ++vt)
            vp[vt] = *(const bf16x8*)&vbB[(vt * 16 + l15) * 4096 + m0n + gs * 8];

        f32x4 dz;
#pragma unroll
        for (int r = 0; r < 4; ++r) dz[r] = 0.0f;

        bf16x8 bp[2];
#pragma unroll
        for (int qt = 0; qt < 2; ++qt) {
            // QK: lane holds P[m=mt*16+g*4+r][q=qt*16+l15]
            f32x4 d0 = __builtin_amdgcn_mfma_f32_16x16x32_bf16(ka, qf[qt], dz, 0, 0, 0);
            f32x4 d1 = __builtin_amdgcn_mfma_f32_16x16x32_bf16(kc, qf[qt], dz, 0, 0, 0);
            float p0[4], p1[4];
#pragma unroll
            for (int r = 0; r < 4; ++r) { p0[r] = __expf(d0[r]); p1[r] = __expf(d1[r]); }
            zreg[qt] += ((p0[0] + p0[1]) + (p0[2] + p0[3]))
                      + ((p1[0] + p1[1]) + (p1[2] + p1[3]));
            // pack: A,B = mt0 pairs; C,D = mt1 pairs (each word = 2 consecutive m)
            const unsigned int A = bfpk(p0[0], p0[1]), B = bfpk(p0[2], p0[3]);
            const unsigned int C = bfpk(p1[0], p1[1]), D = bfpk(p1[2], p1[3]);
            // stage A swap across g-bit0: odd lanes send (A,B), even send (C,D)
            const unsigned int s1 = godd ? A : C;
            const unsigned int s2 = godd ? B : D;
            const unsigned int r1 = __shfl_xor(s1, 16);
            const unsigned int r2 = __shfl_xor(s2, 16);
            union { unsigned int u[4]; bf16x8 v; } pw;
            pw.u[0] = godd ? r1 : A;
            pw.u[1] = godd ? r2 : B;
            pw.u[2] = godd ? C : r1;
            pw.u[3] = godd ? D : r2;
            bp[qt] = pw.v;   // m-slice tau(g)*8..+7 for q=qt*16+l15
        }

        // PV: V A-frags loaded at slice tau(g) -> contraction order matches
        __builtin_amdgcn_s_setprio(1);
#pragma unroll
        for (int vt = 0; vt < 4; ++vt) {
            acc[0][vt] = __builtin_amdgcn_mfma_f32_16x16x32_bf16(vc[vt], bp[0], acc[0][vt], 0, 0, 0);
            acc[1][vt] = __builtin_amdgcn_mfma_f32_16x16x32_bf16(vc[vt], bp[1], acc[1][vt], 0, 0, 0);
        }
        __builtin_amdgcn_s_setprio(0);
        m0 = m0n;
    }

    // z: combine over g-lanes, one atomic per wave per q
#pragma unroll
    for (int qt = 0; qt < 2; ++qt) {
        float z = zreg[qt];
        z += __shfl_xor(z, 16);
        z += __shfl_xor(z, 32);
        if (g == 0) atomicAdd(&zls[qt * 16 + l15], z);
    }

    // per-wave partial O -> LDS
#pragma unroll
    for (int qt = 0; qt < 2; ++qt)
#pragma unroll
        for (int vt = 0; vt < 4; ++vt)
#pragma unroll
            for (int r = 0; r < 4; ++r)
                osum[w][vt * 16 + g * 4 + r][qt * 16 + l15] = acc[qt][vt][r];

    // SE gate (wave 0, tiny)
    if (t < 64) {
        float hreg[4];
#pragma unroll
        for (int j = 0; j < 4; ++j) {
            float hh = b1[j];
            for (int c = 0; c < 64; ++c) hh += W1[j * 64 + c] * avgs[c];
            hreg[j] = fmaxf(hh, 0.0f);
        }
        float gg = b2[t];
#pragma unroll
        for (int j = 0; j < 4; ++j) gg += W2[t * 4 + j] * hreg[j];
        gls[t] = 1.0f / (1.0f + __expf(-gg));
    }
    __syncthreads();

    // combine 4 wave-partials + scale + gate + store
    {
        const int v = t >> 2;
        const int qb4 = (t & 3) * 8;
        const float gv = gls[v];
        float* orow = out + (b * 64 + v) * 4096 + q0 + qb4;
#pragma unroll
        for (int j = 0; j < 8; ++j) {
            const int q = qb4 + j;
            const float s = (osum[0][v][q] + osum[1][v][q])
                          + (osum[2][v][q] + osum[3][v][q]);
            orow[j] = s * (1.0f / zls[q]) * gv;
        }
    }
}

extern "C" void kernel_launch(void* const* d_in, const int* in_sizes, int n_in,
                              void* d_out, int out_size, void* d_ws, size_t ws_size,
                              hipStream_t stream) {
    const float* x  = (const float*)d_in[0];
    const float* Wq = (const float*)d_in[1];
    const float* bq = (const float*)d_in[2];
    const float* Wk = (const float*)d_in[3];
    const float* bk = (const float*)d_in[4];
    const float* Wv = (const float*)d_in[5];
    const float* bv = (const float*)d_in[6];
    const float* W1 = (const float*)d_in[7];
    const float* b1 = (const float*)d_in[8];
    const float* W2 = (const float*)d_in[9];
    const float* b2 = (const float*)d_in[10];

    unsigned short* wsu = (unsigned short*)d_ws;
    unsigned short* Qb = wsu + WS_QB;
    unsigned short* Kb = wsu + WS_KB;
    unsigned short* Vb = wsu + WS_VB;
    float* avg = (float*)(wsu + WS_AVG_U);
    float* out = (float*)d_out;

    hipMemsetAsync(avg, 0, 256 * sizeof(float), stream);
    proj_kernel<<<1280, 256, 0, stream>>>(x, Wq, bq, Wk, bk, Wv, bv, Qb, Kb, Vb, avg);
    attn_kernel<<<512, 256, 0, stream>>>(Qb, Kb, Vb, avg, W1, b1, W2, b2, out);
}

// Round 8
// 116.434 us; speedup vs baseline: 1.0105x; 1.0098x over previous
//
#include <hip/hip_runtime.h>
#include <hip/hip_bf16.h>

typedef __attribute__((ext_vector_type(8))) short bf16x8;
typedef __attribute__((ext_vector_type(4))) float f32x4;
typedef __attribute__((ext_vector_type(4))) unsigned short u16x4;
typedef __attribute__((ext_vector_type(8))) unsigned short u16x8;

// ws layout (ushort units):
//   Qb [4][4096][8]  @ 0        bf16, pre-scaled by 0.125, [n][c] fragment layout
//   Kb [4][4096][8]  @ 131072   bf16, [m][c]
//   Vb [4][64][4096] @ 262144   bf16, [v][n]
//   avg floats [4][64] @ ushort offset 1310720 (zeroed via memsetAsync)
#define WS_QB 0
#define WS_KB 131072
#define WS_VB 262144
#define WS_AVG_U 1310720

__device__ __forceinline__ unsigned short bf_hi(float x) {
    __hip_bfloat16 h = __float2bfloat16(x);
    return *reinterpret_cast<unsigned short*>(&h);
}
__device__ __forceinline__ unsigned int bfpk(float lo, float hi) {
    return (unsigned int)bf_hi(lo) | ((unsigned int)bf_hi(hi) << 16);
}

// ---------------------------------------------------------------------------
// Kernel A: QKV projection (MFMA) + channel means. grid = 1280 x 256.
// ---------------------------------------------------------------------------
__global__ __launch_bounds__(256) void proj_kernel(
    const float* __restrict__ x,
    const float* __restrict__ Wq, const float* __restrict__ bq,
    const float* __restrict__ Wk, const float* __restrict__ bk,
    const float* __restrict__ Wv, const float* __restrict__ bv,
    unsigned short* __restrict__ Qb, unsigned short* __restrict__ Kb,
    unsigned short* __restrict__ Vb, float* __restrict__ avg)
{
    __shared__ __align__(16) unsigned short Wls[16 * 72];

    const int tid = threadIdx.x;
    const int w = tid >> 6;
    const int l = tid & 63;
    const int g = l >> 4;
    const int l15 = l & 15;

    const int tile = blockIdx.x >> 8;
    const int pair = blockIdx.x & 255;
    const int b = pair >> 6;
    const int n0 = (pair & 63) << 6;
    const int n = n0 + w * 16 + l15;
    const float* xb = x + b * 262144;

    float xr[2][8];
#pragma unroll
    for (int kcb = 0; kcb < 2; ++kcb)
#pragma unroll
        for (int j = 0; j < 8; ++j)
            xr[kcb][j] = xb[(kcb * 32 + g * 8 + j) * 4096 + n];

#pragma unroll
    for (int i = 0; i < 4; ++i) {
        const int idx = i * 256 + tid;
        const int row = idx >> 6, col = idx & 63;
        float wv;
        if (tile == 0) wv = (row < 8) ? Wq[row * 64 + col] : Wk[(row - 8) * 64 + col];
        else           wv = Wv[((tile - 1) * 16 + row) * 64 + col];
        Wls[row * 72 + col] = bf_hi(wv);
    }
    __syncthreads();

    bf16x8 bfr[2];
#pragma unroll
    for (int kcb = 0; kcb < 2; ++kcb)
#pragma unroll
        for (int j = 0; j < 8; ++j)
            bfr[kcb][j] = (short)bf_hi(xr[kcb][j]);

    const bf16x8 a0 = *(const bf16x8*)&Wls[l15 * 72 + g * 8];
    const bf16x8 a1 = *(const bf16x8*)&Wls[l15 * 72 + 32 + g * 8];
    f32x4 acc;
#pragma unroll
    for (int r = 0; r < 4; ++r) acc[r] = 0.0f;
    acc = __builtin_amdgcn_mfma_f32_16x16x32_bf16(a0, bfr[0], acc, 0, 0, 0);
    acc = __builtin_amdgcn_mfma_f32_16x16x32_bf16(a1, bfr[1], acc, 0, 0, 0);

    if (tile == 0) {
        u16x4 ov;
        if (g < 2) {
#pragma unroll
            for (int r = 0; r < 4; ++r) ov[r] = bf_hi((acc[r] + bq[g * 4 + r]) * 0.125f);
            *(u16x4*)&Qb[(b * 4096 + n) * 8 + g * 4] = ov;
        } else {
#pragma unroll
            for (int r = 0; r < 4; ++r) ov[r] = bf_hi(acc[r] + bk[(g - 2) * 4 + r]);
            *(u16x4*)&Kb[(b * 4096 + n) * 8 + (g - 2) * 4] = ov;
        }
        const int c = tid >> 2;
        const float* xrow = xb + c * 4096 + n0 + ((tid & 3) << 4);
        float s = 0.0f;
#pragma unroll
        for (int k = 0; k < 4; ++k) {
            const float4 v = *(const float4*)&xrow[k * 4];
            s += (v.x + v.y) + (v.z + v.w);
        }
        s += __shfl_xor(s, 1);
        s += __shfl_xor(s, 2);
        if ((tid & 3) == 0) atomicAdd(&avg[b * 64 + c], s * (1.0f / 4096.0f));
    } else {
#pragma unroll
        for (int r = 0; r < 4; ++r) {
            const int v = (tile - 1) * 16 + g * 4 + r;
            Vb[(b * 64 + v) * 4096 + n] = bf_hi(acc[r] + bv[v]);
        }
    }
}

// ---------------------------------------------------------------------------
// Kernel B: attention + gate. grid = 512 (XCD-chunk-swizzled), 512 thr/8 waves,
// 2 blocks/CU = 16 waves/CU (R7 had 8: latency exposed). Block = (b, 32-q tile).
// Each wave owns m-chunks c = w + 8*ci (16 chunks of 32 m), fully in-register:
//   QK MFMA (K direct from global) -> exp -> pack + 1 shfl_xor(16) redistrib
//   (m-slice tau(g)=bitrev(g), absorbed into V A-frag load offset) -> PV MFMA.
// No in-loop LDS/barriers. Epilogue: two-stage partial-O combine in LDS.
// ---------------------------------------------------------------------------
__global__ __launch_bounds__(512, 4) void attn_kernel(
    const unsigned short* __restrict__ Qb, const unsigned short* __restrict__ Kb,
    const unsigned short* __restrict__ Vb, const float* __restrict__ avg,
    const float* __restrict__ W1, const float* __restrict__ b1,
    const float* __restrict__ W2, const float* __restrict__ b2,
    float* __restrict__ out)
{
    __shared__ float osum[4][64][33];   // [wave 0-3][v][q+pad]; waves 4-7 add in
    __shared__ float zls[32], gls[64], avgs[64];

    const int t = threadIdx.x;
    const int w = t >> 6;
    const int l = t & 63;
    const int g = l >> 4;
    const int l15 = l & 15;
    const int godd = g & 1;
    const int gs = (godd << 1) | (g >> 1);   // tau(g): bit-reversed 2-bit g

    // bijective XCD chunk swizzle (512 % 8 == 0)
    const int wg = (blockIdx.x & 7) * 64 + (blockIdx.x >> 3);
    const int b = wg >> 7;
    const int q0 = (wg & 127) << 5;

    if (t < 32) zls[t] = 0.0f;
    if (t < 64) avgs[t] = avg[b * 64 + t];
    __syncthreads();   // init visible before post-loop atomics/reads

    bf16x8 zf = {};
    bf16x8 qf[2];
#pragma unroll
    for (int qt = 0; qt < 2; ++qt) {
        bf16x8 v = *(const bf16x8*)&Qb[(b * 4096 + q0 + qt * 16 + l15) * 8];
        qf[qt] = (g == 0) ? v : zf;
    }

    const unsigned short* kb = Kb + b * 4096 * 8;
    const unsigned short* vbB = Vb + (b * 64) * 4096;

    // prefetch chunk ci=0 (m0 = 32*w); V frags at slice tau(g)
    int m0 = w * 32;
    bf16x8 kpa = zf, kpb = zf;
    if (g == 0) {
        kpa = *(const bf16x8*)&kb[(m0 + l15) * 8];
        kpb = *(const bf16x8*)&kb[(m0 + 16 + l15) * 8];
    }
    bf16x8 vp[4];
#pragma unroll
    for (int vt = 0; vt < 4; ++vt)
        vp[vt] = *(const bf16x8*)&vbB[(vt * 16 + l15) * 4096 + m0 + gs * 8];

    f32x4 acc[2][4];
#pragma unroll
    for (int qt = 0; qt < 2; ++qt)
#pragma unroll
        for (int vt = 0; vt < 4; ++vt)
#pragma unroll
            for (int r = 0; r < 4; ++r) acc[qt][vt][r] = 0.0f;
    float zreg[2] = {0.f, 0.f};

    for (int ci = 0; ci < 16; ++ci) {
        const bf16x8 ka = kpa, kc = kpb;
        bf16x8 vc[4];
#pragma unroll
        for (int vt = 0; vt < 4; ++vt) vc[vt] = vp[vt];

        // issue next chunk's loads (covered by this chunk's compute)
        const int m0n = (ci < 15) ? (w + 8 * (ci + 1)) * 32 : m0;
        if (g == 0) {
            kpa = *(const bf16x8*)&kb[(m0n + l15) * 8];
            kpb = *(const bf16x8*)&kb[(m0n + 16 + l15) * 8];
        }
#pragma unroll
        for (int vt = 0; vt < 4; ++vt)
            vp[vt] = *(const bf16x8*)&vbB[(vt * 16 + l15) * 4096 + m0n + gs * 8];

        f32x4 dz;
#pragma unroll
        for (int r = 0; r < 4; ++r) dz[r] = 0.0f;

        bf16x8 bp[2];
#pragma unroll
        for (int qt = 0; qt < 2; ++qt) {
            // QK: lane holds P[m=mt*16+g*4+r][q=qt*16+l15]
            f32x4 d0 = __builtin_amdgcn_mfma_f32_16x16x32_bf16(ka, qf[qt], dz, 0, 0, 0);
            f32x4 d1 = __builtin_amdgcn_mfma_f32_16x16x32_bf16(kc, qf[qt], dz, 0, 0, 0);
            float p0[4], p1[4];
#pragma unroll
            for (int r = 0; r < 4; ++r) { p0[r] = __expf(d0[r]); p1[r] = __expf(d1[r]); }
            zreg[qt] += ((p0[0] + p0[1]) + (p0[2] + p0[3]))
                      + ((p1[0] + p1[1]) + (p1[2] + p1[3]));
            // pack: A,B = mt0 pairs; C,D = mt1 pairs (each word = 2 consecutive m)
            const unsigned int A = bfpk(p0[0], p0[1]), B = bfpk(p0[2], p0[3]);
            const unsigned int C = bfpk(p1[0], p1[1]), D = bfpk(p1[2], p1[3]);
            // swap across g-bit0: odd lanes send (A,B), even send (C,D)
            const unsigned int s1 = godd ? A : C;
            const unsigned int s2 = godd ? B : D;
            const unsigned int r1 = __shfl_xor(s1, 16);
            const unsigned int r2 = __shfl_xor(s2, 16);
            union { unsigned int u[4]; bf16x8 v; } pw;
            pw.u[0] = godd ? r1 : A;
            pw.u[1] = godd ? r2 : B;
            pw.u[2] = godd ? C : r1;
            pw.u[3] = godd ? D : r2;
            bp[qt] = pw.v;   // m-slice tau(g)*8..+7 for q=qt*16+l15
        }

        // PV: V A-frags loaded at slice tau(g) -> contraction order matches
        __builtin_amdgcn_s_setprio(1);
#pragma unroll
        for (int vt = 0; vt < 4; ++vt) {
            acc[0][vt] = __builtin_amdgcn_mfma_f32_16x16x32_bf16(vc[vt], bp[0], acc[0][vt], 0, 0, 0);
            acc[1][vt] = __builtin_amdgcn_mfma_f32_16x16x32_bf16(vc[vt], bp[1], acc[1][vt], 0, 0, 0);
        }
        __builtin_amdgcn_s_setprio(0);
        m0 = m0n;
    }

    // z: combine over g-lanes, one atomic per wave per q
#pragma unroll
    for (int qt = 0; qt < 2; ++qt) {
        float z = zreg[qt];
        z += __shfl_xor(z, 16);
        z += __shfl_xor(z, 32);
        if (g == 0) atomicAdd(&zls[qt * 16 + l15], z);
    }

    // stage 1: waves 0-3 write partial O
    if (w < 4) {
#pragma unroll
        for (int qt = 0; qt < 2; ++qt)
#pragma unroll
            for (int vt = 0; vt < 4; ++vt)
#pragma unroll
                for (int r = 0; r < 4; ++r)
                    osum[w][vt * 16 + g * 4 + r][qt * 16 + l15] = acc[qt][vt][r];
    }
    // SE gate (wave 0 lanes, tiny)
    if (t < 64) {
        float hreg[4];
#pragma unroll
        for (int j = 0; j < 4; ++j) {
            float hh = b1[j];
            for (int c = 0; c < 64; ++c) hh += W1[j * 64 + c] * avgs[c];
            hreg[j] = fmaxf(hh, 0.0f);
        }
        float gg = b2[t];
#pragma unroll
        for (int j = 0; j < 4; ++j) gg += W2[t * 4 + j] * hreg[j];
        gls[t] = 1.0f / (1.0f + __expf(-gg));
    }
    __syncthreads();

    // stage 2: waves 4-7 add their partials
    if (w >= 4) {
#pragma unroll
        for (int qt = 0; qt < 2; ++qt)
#pragma unroll
            for (int vt = 0; vt < 4; ++vt)
#pragma unroll
                for (int r = 0; r < 4; ++r)
                    osum[w - 4][vt * 16 + g * 4 + r][qt * 16 + l15] += acc[qt][vt][r];
    }
    __syncthreads();

    // combine 4 partials + scale + gate + store (512 threads, 4 q each)
    {
        const int v = t >> 3;
        const int qb4 = (t & 7) * 4;
        const float gv = gls[v];
        float* orow = out + (b * 64 + v) * 4096 + q0 + qb4;
#pragma unroll
        for (int j = 0; j < 4; ++j) {
            const int q = qb4 + j;
            const float s = (osum[0][v][q] + osum[1][v][q])
                          + (osum[2][v][q] + osum[3][v][q]);
            orow[j] = s * (1.0f / zls[q]) * gv;
        }
    }
}

extern "C" void kernel_launch(void* const* d_in, const int* in_sizes, int n_in,
                              void* d_out, int out_size, void* d_ws, size_t ws_size,
                              hipStream_t stream) {
    const float* x  = (const float*)d_in[0];
    const float* Wq = (const float*)d_in[1];
    const float* bq = (const float*)d_in[2];
    const float* Wk = (const float*)d_in[3];
    const float* bk = (const float*)d_in[4];
    const float* Wv = (const float*)d_in[5];
    const float* bv = (const float*)d_in[6];
    const float* W1 = (const float*)d_in[7];
    const float* b1 = (const float*)d_in[8];
    const float* W2 = (const float*)d_in[9];
    const float* b2 = (const float*)d_in[10];

    unsigned short* wsu = (unsigned short*)d_ws;
    unsigned short* Qb = wsu + WS_QB;
    unsigned short* Kb = wsu + WS_KB;
    unsigned short* Vb = wsu + WS_VB;
    float* avg = (float*)(wsu + WS_AVG_U);
    float* out = (float*)d_out;

    hipMemsetAsync(avg, 0, 256 * sizeof(float), stream);
    proj_kernel<<<1280, 256, 0, stream>>>(x, Wq, bq, Wk, bk, Wv, bv, Qb, Kb, Vb, avg);
    attn_kernel<<<512, 512, 0, stream>>>(Qb, Kb, Vb, avg, W1, b1, W2, b2, out);
}